// Round 5
// baseline (461.380 us; speedup 1.0000x reference)
//
#include <hip/hip_runtime.h>

#define IMG_H 1024
#define IMG_W 1024
#define RPB   16      // output rows per block
#define TPB   256     // threads per block; each thread owns 4 columns

struct HS  { float x[4], y[4], xx[4], yy[4], xy[4]; };
struct Raw { float x[6], y[6]; };

__device__ __forceinline__ void zero_hs(HS& h)
{
#pragma unroll
    for (int j = 0; j < 4; ++j) { h.x[j]=0.f; h.y[j]=0.f; h.xx[j]=0.f; h.yy[j]=0.f; h.xy[j]=0.f; }
}

// Pure loads, NO conditionals: halo addresses pre-clamped (cl, cr), masking
// deferred to hsum. Keeps all 6 VMEM ops hoistable by the scheduler.
__device__ __forceinline__ void load_raw(const float* __restrict__ xr,
                                         const float* __restrict__ yr,
                                         int c, int cl, int cr, Raw& r)
{
    float4 xv = *reinterpret_cast<const float4*>(xr + c);
    float4 yv = *reinterpret_cast<const float4*>(yr + c);
    r.x[0] = xr[cl]; r.x[5] = xr[cr];
    r.y[0] = yr[cl]; r.y[5] = yr[cr];
    r.x[1] = xv.x; r.x[2] = xv.y; r.x[3] = xv.z; r.x[4] = xv.w;
    r.y[1] = yv.x; r.y[2] = yv.y; r.y[3] = yv.z; r.y[4] = yv.w;
}

// Consume a Raw (loaded in a PREVIOUS step) into horizontal 3-sums.
__device__ __forceinline__ void hsum(const Raw& r, float lm, float rm, HS& h)
{
    float xs[6], ys[6];
    xs[0] = r.x[0] * lm; ys[0] = r.y[0] * lm;
    xs[5] = r.x[5] * rm; ys[5] = r.y[5] * rm;
#pragma unroll
    for (int k = 1; k < 5; ++k) { xs[k] = r.x[k]; ys[k] = r.y[k]; }

    float pxx[6], pyy[6], pxy[6];
#pragma unroll
    for (int k = 0; k < 6; ++k) {
        pxx[k] = xs[k] * xs[k];
        pyy[k] = ys[k] * ys[k];
        pxy[k] = xs[k] * ys[k];
    }
#pragma unroll
    for (int j = 0; j < 4; ++j) {
        h.x[j]  = xs[j]  + xs[j + 1]  + xs[j + 2];
        h.y[j]  = ys[j]  + ys[j + 1]  + ys[j + 2];
        h.xx[j] = pxx[j] + pxx[j + 1] + pxx[j + 2];
        h.yy[j] = pyy[j] + pyy[j + 1] + pyy[j + 2];
        h.xy[j] = pxy[j] + pxy[j + 1] + pxy[j + 2];
    }
}

// Scaled SSIM (both factors of num/den multiplied by 81; EPS by 6561):
//   num = (2*sx*sy + 81*C1) * (18*sxy - 2*sx*sy + 81*C2)
//   den = (sx^2+sy^2 + 81*C1) * (9*(sxx+syy) - (sx^2+sy^2) + 81*C2) + 6561*EPS
__device__ __forceinline__ void accum(const HS& A, const HS& B, const HS& C, float& acc)
{
    const float c1s  = 81.0f * 1e-4f;
    const float c2s  = 81.0f * 9e-4f;
    const float epss = 6561.0f * 1e-8f;
#pragma unroll
    for (int j = 0; j < 4; ++j) {
        const float sx  = A.x[j]  + B.x[j]  + C.x[j];
        const float sy  = A.y[j]  + B.y[j]  + C.y[j];
        const float sxx = A.xx[j] + B.xx[j] + C.xx[j];
        const float syy = A.yy[j] + B.yy[j] + C.yy[j];
        const float sxy = A.xy[j] + B.xy[j] + C.xy[j];

        const float t1 = sx * sy;
        const float t2 = fmaf(sx, sx, sy * sy);
        const float s2 = sxx + syy;
        const float An = fmaf(2.0f, t1, c1s);
        const float Bn = fmaf(-2.0f, t1, fmaf(18.0f, sxy, c2s));
        const float Xd = t2 + c1s;
        const float Yd = fmaf(9.0f, s2, c2s - t2);
        const float den = fmaf(Xd, Yd, epss);
        const float num = An * Bn;
        acc = fmaf(num, __builtin_amdgcn_rcpf(den), acc);
    }
}

// Cap VGPR at 128 (4 waves/EU): pressure estimate ~110 for 2 Raw + 3 HS.
__global__ __launch_bounds__(TPB, 4)
void ssim_map_sum_kernel(const float* __restrict__ x,
                         const float* __restrict__ y,
                         float* __restrict__ ws_sum)
{
    const int rb = blockIdx.x;
    const int n  = blockIdx.y;
    const int r0 = rb * RPB;
    const int c  = (int)threadIdx.x * 4;

    const int   cl = (c > 0) ? c - 1 : 0;
    const int   cr = (c + 4 < IMG_W) ? c + 4 : IMG_W - 1;
    const float lm = (c > 0) ? 1.0f : 0.0f;
    const float rm = (c + 4 < IMG_W) ? 1.0f : 0.0f;

    const float* xi = x + (size_t)n * IMG_H * IMG_W;
    const float* yi = y + (size_t)n * IMG_H * IMG_W;

    HS hA, hB, hC;
    Raw raw0, raw1;

    // Prologue: hA = hsum(row r0-1) (or zero), hB = hsum(row r0),
    // raw0 = raw(row r0+1) -- prefetched, consumed in step k=0.
    if (r0 > 0) {
        Raw rp;
        load_raw(xi + (size_t)(r0 - 1) * IMG_W, yi + (size_t)(r0 - 1) * IMG_W, c, cl, cr, rp);
        hsum(rp, lm, rm, hA);
    } else {
        zero_hs(hA);
    }
    {
        Raw rq;
        load_raw(xi + (size_t)r0 * IMG_W, yi + (size_t)r0 * IMG_W, c, cl, cr, rq);
        hsum(rq, lm, rm, hB);
    }
    load_raw(xi + (size_t)(r0 + 1) * IMG_W, yi + (size_t)(r0 + 1) * IMG_W, c, cl, cr, raw0);

    float acc = 0.0f;

    // Step k (output row r0+k): issue loads for row r0+k+2 into ROUT, consume
    // RIN (row r0+k+1, loaded LAST step) into R, accumulate. Loads have a full
    // step (~300 cyc VALU) of slack before their vmcnt wait.
#define STEP(P, Q, R, RIN, ROUT, k)                                               \
    load_raw(xi + (size_t)(r0 + (k) + 2) * IMG_W,                                 \
             yi + (size_t)(r0 + (k) + 2) * IMG_W, c, cl, cr, ROUT);               \
    hsum(RIN, lm, rm, R);                                                         \
    accum(P, Q, R, acc);

    // k = 0..11: rows r0+2 .. r0+13 loaded, all in-bounds. Period-6 pattern
    // (3 HS roles x 2 raw buffers) -> zero rotation movs.
    for (int ii = 0; ii < 12; ii += 6) {
        STEP(hA, hB, hC, raw0, raw1, ii + 0)
        STEP(hB, hC, hA, raw1, raw0, ii + 1)
        STEP(hC, hA, hB, raw0, raw1, ii + 2)
        STEP(hA, hB, hC, raw1, raw0, ii + 3)
        STEP(hB, hC, hA, raw0, raw1, ii + 4)
        STEP(hC, hA, hB, raw1, raw0, ii + 5)
    }
    STEP(hA, hB, hC, raw0, raw1, 12)     // loads row r0+14
    STEP(hB, hC, hA, raw1, raw0, 13)     // loads row r0+15
#undef STEP

    // k = 14: would load row r0+16 (OOB only for the last block-row) -> clamp
    // the address (load is unconditional/hoistable), mask at consume below.
    {
        const int rr = (r0 + 16 < IMG_H) ? r0 + 16 : IMG_H - 1;
        load_raw(xi + (size_t)rr * IMG_W, yi + (size_t)rr * IMG_W, c, cl, cr, raw1);
        hsum(raw0, lm, rm, hB);          // row r0+15
        accum(hC, hA, hB, acc);          // output row r0+14
    }

    // k = 15 (final output row r0+15): consume raw1 as row r0+16, masked.
    if (r0 + 16 < IMG_H) hsum(raw1, lm, rm, hC);
    else                 zero_hs(hC);
    accum(hA, hB, hC, acc);

    // wave (64-lane) reduction
#pragma unroll
    for (int off = 32; off > 0; off >>= 1)
        acc += __shfl_down(acc, off);

    __shared__ float red[TPB / 64];
    const int lane = (int)threadIdx.x & 63;
    const int wave = (int)threadIdx.x >> 6;
    if (lane == 0) red[wave] = acc;
    __syncthreads();
    if (threadIdx.x == 0) {
        float s = 0.0f;
#pragma unroll
        for (int w = 0; w < TPB / 64; ++w) s += red[w];
        atomicAdd(ws_sum, s);
    }
}

__global__ void ssim_finalize_kernel(const float* __restrict__ ws_sum,
                                     float* __restrict__ out,
                                     float inv_count)
{
    out[0] = 1.0f - ws_sum[0] * inv_count;
}

extern "C" void kernel_launch(void* const* d_in, const int* in_sizes, int n_in,
                              void* d_out, int out_size, void* d_ws, size_t ws_size,
                              hipStream_t stream)
{
    const float* x = (const float*)d_in[0];
    const float* y = (const float*)d_in[1];
    float* out  = (float*)d_out;
    float* wsum = (float*)d_ws;

    const long long total = (long long)in_sizes[0];       // 32*1024*1024
    const int N = (int)(total / ((long long)IMG_H * IMG_W));

    hipMemsetAsync(wsum, 0, sizeof(float), stream);

    dim3 grid(IMG_H / RPB, N);
    ssim_map_sum_kernel<<<grid, TPB, 0, stream>>>(x, y, wsum);

    ssim_finalize_kernel<<<1, 1, 0, stream>>>(wsum, out, 1.0f / (float)total);
}

// Round 6
// 419.010 us; speedup vs baseline: 1.1011x; 1.1011x over previous
//
#include <hip/hip_runtime.h>

#define IMG_H  1024
#define IMG_W  1024
#define TILE_C 128               // output cols per block
#define RPB    16                // output rows per block
#define TPB    128
#define SROWS  (RPB + 2)         // 18 staged rows (r0-1 .. r0+16)
#define SCOL4  ((TILE_C + 8) / 4)// 34 staged float4 per row (cols c0-4 .. c0+131)
#define SCOLS  (TILE_C + 8)      // 136 floats per staged row

struct HS { float x[4], y[4], xx[4], yy[4], xy[4]; };

// Horizontal 3-sums for 4 output cols from one staged LDS row.
// LDS col (t+4) holds tile col t; edge zeros were staged, so no masks here.
__device__ __forceinline__ void hsum_lds(const float* __restrict__ rx,
                                         const float* __restrict__ ry,
                                         int j0, HS& h)
{
    float xs[6], ys[6];
    const float4 xv = *reinterpret_cast<const float4*>(rx + j0 + 4);
    const float4 yv = *reinterpret_cast<const float4*>(ry + j0 + 4);
    xs[0] = rx[j0 + 3]; ys[0] = ry[j0 + 3];
    xs[1] = xv.x; xs[2] = xv.y; xs[3] = xv.z; xs[4] = xv.w;
    ys[1] = yv.x; ys[2] = yv.y; ys[3] = yv.z; ys[4] = yv.w;
    xs[5] = rx[j0 + 8]; ys[5] = ry[j0 + 8];

    float pxx[6], pyy[6], pxy[6];
#pragma unroll
    for (int k = 0; k < 6; ++k) {
        pxx[k] = xs[k] * xs[k];
        pyy[k] = ys[k] * ys[k];
        pxy[k] = xs[k] * ys[k];
    }
#pragma unroll
    for (int j = 0; j < 4; ++j) {
        h.x[j]  = xs[j]  + xs[j + 1]  + xs[j + 2];
        h.y[j]  = ys[j]  + ys[j + 1]  + ys[j + 2];
        h.xx[j] = pxx[j] + pxx[j + 1] + pxx[j + 2];
        h.yy[j] = pyy[j] + pyy[j + 1] + pyy[j + 2];
        h.xy[j] = pxy[j] + pxy[j + 1] + pxy[j + 2];
    }
}

// Scaled SSIM (both num/den factors x81, EPS x6561; verified absmax==0 R2-R5):
//   num = (2*sx*sy + 81*C1) * (18*sxy - 2*sx*sy + 81*C2)
//   den = (sx^2+sy^2 + 81*C1) * (9*(sxx+syy) - (sx^2+sy^2) + 81*C2) + 6561*EPS
__device__ __forceinline__ void accum(const HS& A, const HS& B, const HS& C, float& acc)
{
    const float c1s  = 81.0f * 1e-4f;
    const float c2s  = 81.0f * 9e-4f;
    const float epss = 6561.0f * 1e-8f;
#pragma unroll
    for (int j = 0; j < 4; ++j) {
        const float sx  = A.x[j]  + B.x[j]  + C.x[j];
        const float sy  = A.y[j]  + B.y[j]  + C.y[j];
        const float sxx = A.xx[j] + B.xx[j] + C.xx[j];
        const float syy = A.yy[j] + B.yy[j] + C.yy[j];
        const float sxy = A.xy[j] + B.xy[j] + C.xy[j];

        const float t1 = sx * sy;
        const float t2 = fmaf(sx, sx, sy * sy);
        const float s2 = sxx + syy;
        const float An = fmaf(2.0f, t1, c1s);
        const float Bn = fmaf(-2.0f, t1, fmaf(18.0f, sxy, c2s));
        const float Xd = t2 + c1s;
        const float Yd = fmaf(9.0f, s2, c2s - t2);
        const float den = fmaf(Xd, Yd, epss);
        const float num = An * Bn;
        acc = fmaf(num, __builtin_amdgcn_rcpf(den), acc);
    }
}

__global__ __launch_bounds__(TPB)
void ssim_map_sum_kernel(const float* __restrict__ x,
                         const float* __restrict__ y,
                         float* __restrict__ ws_sum)
{
    __shared__ float sx[SROWS][SCOLS];
    __shared__ float sy[SROWS][SCOLS];

    const int c0 = blockIdx.x * TILE_C;
    const int r0 = blockIdx.y * RPB;
    const int n  = blockIdx.z;
    const int tid = (int)threadIdx.x;

    const float* xi = x + (size_t)n * IMG_H * IMG_W;
    const float* yi = y + (size_t)n * IMG_H * IMG_W;

    // ---- Stage phase: burst of independent float4 loads (MLP!), edge zeros
    // written into LDS so compute phase needs no masks at all.
    for (int idx = tid; idx < SROWS * SCOL4; idx += TPB) {
        const int row = idx / SCOL4;           // 0..17
        const int c4  = idx - row * SCOL4;     // 0..33
        const int grow = r0 - 1 + row;
        const int gcol = c0 - 4 + c4 * 4;      // float4-aligned; OOB is whole-vec
        const int crow = min(max(grow, 0), IMG_H - 1);
        const int ccol = min(max(gcol, 0), IMG_W - 4);
        const float m = (grow >= 0 && grow < IMG_H && gcol >= 0 && gcol + 3 < IMG_W)
                        ? 1.0f : 0.0f;
        const float4 xv = *reinterpret_cast<const float4*>(xi + (size_t)crow * IMG_W + ccol);
        const float4 yv = *reinterpret_cast<const float4*>(yi + (size_t)crow * IMG_W + ccol);
        float* dx = &sx[row][c4 * 4];
        float* dy = &sy[row][c4 * 4];
        dx[0] = xv.x * m; dx[1] = xv.y * m; dx[2] = xv.z * m; dx[3] = xv.w * m;
        dy[0] = yv.x * m; dy[1] = yv.y * m; dy[2] = yv.z * m; dy[3] = yv.w * m;
    }
    __syncthreads();

    // ---- Compute phase: thread -> 4 cols x 4 rows, straight-line.
    const int j0 = (tid & 31) * 4;             // tile col 0..124
    const int g  = (tid >> 5) * 4;             // tile row group base 0,4,8,12
    // input rows (global r0+g-1 .. r0+g+4) == LDS rows g .. g+5

    float acc = 0.0f;
    HS hA, hB, hC;
    hsum_lds(sx[g + 0], sy[g + 0], j0, hA);
    hsum_lds(sx[g + 1], sy[g + 1], j0, hB);
    hsum_lds(sx[g + 2], sy[g + 2], j0, hC);
    accum(hA, hB, hC, acc);                    // out row g+0
    hsum_lds(sx[g + 3], sy[g + 3], j0, hA);
    accum(hB, hC, hA, acc);                    // out row g+1
    hsum_lds(sx[g + 4], sy[g + 4], j0, hB);
    accum(hC, hA, hB, acc);                    // out row g+2
    hsum_lds(sx[g + 5], sy[g + 5], j0, hC);
    accum(hA, hB, hC, acc);                    // out row g+3

    // ---- Reduction: wave shuffle -> LDS -> one atomic per block.
#pragma unroll
    for (int off = 32; off > 0; off >>= 1)
        acc += __shfl_down(acc, off);

    __shared__ float red[TPB / 64];
    const int lane = tid & 63;
    const int wave = tid >> 6;
    __syncthreads();   // reuse of LDS region is not an issue (red is separate)
    if (lane == 0) red[wave] = acc;
    __syncthreads();
    if (tid == 0) {
        float s = 0.0f;
#pragma unroll
        for (int w = 0; w < TPB / 64; ++w) s += red[w];
        atomicAdd(ws_sum, s);
    }
}

__global__ void ssim_finalize_kernel(const float* __restrict__ ws_sum,
                                     float* __restrict__ out,
                                     float inv_count)
{
    out[0] = 1.0f - ws_sum[0] * inv_count;
}

extern "C" void kernel_launch(void* const* d_in, const int* in_sizes, int n_in,
                              void* d_out, int out_size, void* d_ws, size_t ws_size,
                              hipStream_t stream)
{
    const float* x = (const float*)d_in[0];
    const float* y = (const float*)d_in[1];
    float* out  = (float*)d_out;
    float* wsum = (float*)d_ws;

    const long long total = (long long)in_sizes[0];       // 32*1024*1024
    const int N = (int)(total / ((long long)IMG_H * IMG_W));

    hipMemsetAsync(wsum, 0, sizeof(float), stream);

    dim3 grid(IMG_W / TILE_C, IMG_H / RPB, N);
    ssim_map_sum_kernel<<<grid, TPB, 0, stream>>>(x, y, wsum);

    ssim_finalize_kernel<<<1, 1, 0, stream>>>(wsum, out, 1.0f / (float)total);
}

// Round 7
// 276.976 us; speedup vs baseline: 1.6658x; 1.5128x over previous
//
#include <hip/hip_runtime.h>

#define IMG_H 1024
#define IMG_W 1024
#define RPB   8       // output rows per block
#define TPB   256     // each thread owns 4 columns

struct HS { float x[4], y[4], xx[4], yy[4], xy[4]; };

__device__ __forceinline__ void zero_hs(HS& h)
{
#pragma unroll
    for (int j = 0; j < 4; ++j) { h.x[j]=0.f; h.y[j]=0.f; h.xx[j]=0.f; h.yy[j]=0.f; h.xy[j]=0.f; }
}

// Horizontal 3-sums from 6 inputs (halo scalars already masked by caller).
__device__ __forceinline__ void hsum6(float xl, float4 xv, float xr6,
                                      float yl, float4 yv, float yr6, HS& h)
{
    float xs[6] = { xl, xv.x, xv.y, xv.z, xv.w, xr6 };
    float ys[6] = { yl, yv.x, yv.y, yv.z, yv.w, yr6 };

    float pxx[6], pyy[6], pxy[6];
#pragma unroll
    for (int k = 0; k < 6; ++k) {
        pxx[k] = xs[k] * xs[k];
        pyy[k] = ys[k] * ys[k];
        pxy[k] = xs[k] * ys[k];
    }
#pragma unroll
    for (int j = 0; j < 4; ++j) {
        h.x[j]  = xs[j]  + xs[j + 1]  + xs[j + 2];
        h.y[j]  = ys[j]  + ys[j + 1]  + ys[j + 2];
        h.xx[j] = pxx[j] + pxx[j + 1] + pxx[j + 2];
        h.yy[j] = pyy[j] + pyy[j + 1] + pyy[j + 2];
        h.xy[j] = pxy[j] + pxy[j + 1] + pxy[j + 2];
    }
}

// Scaled SSIM (both num/den factors x81, EPS x6561; absmax==0 since R2):
//   num = (2*sx*sy + 81*C1) * (18*sxy - 2*sx*sy + 81*C2)
//   den = (sx^2+sy^2 + 81*C1) * (9*(sxx+syy) - (sx^2+sy^2) + 81*C2) + 6561*EPS
__device__ __forceinline__ void accum(const HS& A, const HS& B, const HS& C, float& acc)
{
    const float c1s  = 81.0f * 1e-4f;
    const float c2s  = 81.0f * 9e-4f;
    const float epss = 6561.0f * 1e-8f;
#pragma unroll
    for (int j = 0; j < 4; ++j) {
        const float sx  = A.x[j]  + B.x[j]  + C.x[j];
        const float sy  = A.y[j]  + B.y[j]  + C.y[j];
        const float sxx = A.xx[j] + B.xx[j] + C.xx[j];
        const float syy = A.yy[j] + B.yy[j] + C.yy[j];
        const float sxy = A.xy[j] + B.xy[j] + C.xy[j];

        const float t1 = sx * sy;
        const float t2 = fmaf(sx, sx, sy * sy);
        const float s2 = sxx + syy;
        const float An = fmaf(2.0f, t1, c1s);
        const float Bn = fmaf(-2.0f, t1, fmaf(18.0f, sxy, c2s));
        const float Xd = t2 + c1s;
        const float Yd = fmaf(9.0f, s2, c2s - t2);
        const float den = fmaf(Xd, Yd, epss);
        const float num = An * Bn;
        acc = fmaf(num, __builtin_amdgcn_rcpf(den), acc);
    }
}

// Cap VGPR at 128 (4 waves/EU). Ping-pong prefetch is 4 named float4s (16
// VGPRs) -- NOT arrays (R5's 6-float array buffers spilled 489 MB to scratch).
__global__ __launch_bounds__(TPB, 4)
void ssim_map_sum_kernel(const float* __restrict__ x,
                         const float* __restrict__ y,
                         float* __restrict__ part)
{
    const int rb = blockIdx.x;
    const int n  = blockIdx.y;
    const int r0 = rb * RPB;
    const int c  = (int)threadIdx.x * 4;

    const int   cl = (c > 0) ? c - 1 : 0;
    const int   cr = (c + 4 < IMG_W) ? c + 4 : IMG_W - 1;
    const float lm = (c > 0) ? 1.0f : 0.0f;
    const float rm = (c + 4 < IMG_W) ? 1.0f : 0.0f;

    const float* xi = x + (size_t)n * IMG_H * IMG_W;
    const float* yi = y + (size_t)n * IMG_H * IMG_W;

    HS hA, hB, hC;

    // ---- Prologue: hA = row r0-1 (or zero), hB = row r0 (immediate loads;
    // latency amortized across 16 blocks/CU).
    if (r0 > 0) {
        const float* xr = xi + (size_t)(r0 - 1) * IMG_W;
        const float* yr = yi + (size_t)(r0 - 1) * IMG_W;
        hsum6(xr[cl] * lm, *reinterpret_cast<const float4*>(xr + c), xr[cr] * rm,
              yr[cl] * lm, *reinterpret_cast<const float4*>(yr + c), yr[cr] * rm, hA);
    } else {
        zero_hs(hA);
    }
    {
        const float* xr = xi + (size_t)r0 * IMG_W;
        const float* yr = yi + (size_t)r0 * IMG_W;
        hsum6(xr[cl] * lm, *reinterpret_cast<const float4*>(xr + c), xr[cr] * rm,
              yr[cl] * lm, *reinterpret_cast<const float4*>(yr + c), yr[cr] * rm, hB);
    }

    // Prefetch row r0+1 main float4s (always in-bounds: r0 <= IMG_H-RPB).
    float4 pxa = *reinterpret_cast<const float4*>(xi + (size_t)(r0 + 1) * IMG_W + c);
    float4 pya = *reinterpret_cast<const float4*>(yi + (size_t)(r0 + 1) * IMG_W + c);
    float4 pxb, pyb;

    float acc = 0.0f;

    // Step k (output row r0+k): FIRST issue float4 prefetch of row r0+k+2 into
    // the other buffer (full step of slack before its wait), THEN consume the
    // buffered row r0+k+1; its halo scalars load now -- L1 hits, since the
    // row's lines were prefetched one step ago.
#define STEP_MAIN(k, PXI, PYI, PXO, PYO, P, Q, R)                                  \
    {                                                                              \
        const float* xw = xi + (size_t)(r0 + (k) + 2) * IMG_W;                     \
        const float* yw = yi + (size_t)(r0 + (k) + 2) * IMG_W;                     \
        PXO = *reinterpret_cast<const float4*>(xw + c);                            \
        PYO = *reinterpret_cast<const float4*>(yw + c);                            \
        const float* xu = xi + (size_t)(r0 + (k) + 1) * IMG_W;                     \
        const float* yu = yi + (size_t)(r0 + (k) + 1) * IMG_W;                     \
        hsum6(xu[cl] * lm, PXI, xu[cr] * rm, yu[cl] * lm, PYI, yu[cr] * rm, R);    \
        accum(P, Q, R, acc);                                                       \
    }

    // k = 0..5: prefetched rows r0+2 .. r0+7 all in-bounds (r0+RPB-1 max).
    STEP_MAIN(0, pxa, pya, pxb, pyb, hA, hB, hC)
    STEP_MAIN(1, pxb, pyb, pxa, pya, hB, hC, hA)
    STEP_MAIN(2, pxa, pya, pxb, pyb, hC, hA, hB)
    STEP_MAIN(3, pxb, pyb, pxa, pya, hA, hB, hC)
    STEP_MAIN(4, pxa, pya, pxb, pyb, hB, hC, hA)
    STEP_MAIN(5, pxb, pyb, pxa, pya, hC, hA, hB)
#undef STEP_MAIN

    // k = 6: prefetch row r0+8 with CLAMPED row (OOB only for last block-row;
    // masked at consume). Consume row r0+7 (in-bounds) normally.
    {
        const int rr = (r0 + 8 < IMG_H) ? r0 + 8 : IMG_H - 1;
        const float* xw = xi + (size_t)rr * IMG_W;
        const float* yw = yi + (size_t)rr * IMG_W;
        pxb = *reinterpret_cast<const float4*>(xw + c);
        pyb = *reinterpret_cast<const float4*>(yw + c);
        const float* xu = xi + (size_t)(r0 + 7) * IMG_W;
        const float* yu = yi + (size_t)(r0 + 7) * IMG_W;
        hsum6(xu[cl] * lm, pxa, xu[cr] * rm, yu[cl] * lm, pya, yu[cr] * rm, hC);
        accum(hA, hB, hC, acc);              // output row r0+6
    }

    // k = 7 (final output row r0+7): consume row r0+8, row-masked; halo
    // scalars use the clamped row pointer (no OOB reads).
    {
        const float rwm = (r0 + 8 < IMG_H) ? 1.0f : 0.0f;
        const int rr = (r0 + 8 < IMG_H) ? r0 + 8 : IMG_H - 1;
        const float* xu = xi + (size_t)rr * IMG_W;
        const float* yu = yi + (size_t)rr * IMG_W;
        float4 xv = pxb, yv = pyb;
        xv.x *= rwm; xv.y *= rwm; xv.z *= rwm; xv.w *= rwm;
        yv.x *= rwm; yv.y *= rwm; yv.z *= rwm; yv.w *= rwm;
        hsum6(xu[cl] * (lm * rwm), xv, xu[cr] * (rm * rwm),
              yu[cl] * (lm * rwm), yv, yu[cr] * (rm * rwm), hA);
        accum(hB, hC, hA, acc);
    }

    // ---- Reduction: wave shuffle -> LDS -> ONE STORE per block (no global
    // atomic: 4096 single-address atomics serialized ~20cyc each in R1-R6).
#pragma unroll
    for (int off = 32; off > 0; off >>= 1)
        acc += __shfl_down(acc, off);

    __shared__ float red[TPB / 64];
    const int lane = (int)threadIdx.x & 63;
    const int wave = (int)threadIdx.x >> 6;
    if (lane == 0) red[wave] = acc;
    __syncthreads();
    if (threadIdx.x == 0) {
        float s = 0.0f;
#pragma unroll
        for (int w = 0; w < TPB / 64; ++w) s += red[w];
        part[blockIdx.y * gridDim.x + blockIdx.x] = s;
    }
}

__global__ __launch_bounds__(256)
void ssim_finalize_kernel(const float* __restrict__ part, int nparts,
                          float* __restrict__ out, float inv_count)
{
    float s = 0.0f;
    for (int i = (int)threadIdx.x; i < nparts; i += 256)
        s += part[i];
#pragma unroll
    for (int off = 32; off > 0; off >>= 1)
        s += __shfl_down(s, off);

    __shared__ float red[4];
    const int lane = (int)threadIdx.x & 63;
    const int wave = (int)threadIdx.x >> 6;
    if (lane == 0) red[wave] = s;
    __syncthreads();
    if (threadIdx.x == 0) {
        float t = red[0] + red[1] + red[2] + red[3];
        out[0] = 1.0f - t * inv_count;
    }
}

extern "C" void kernel_launch(void* const* d_in, const int* in_sizes, int n_in,
                              void* d_out, int out_size, void* d_ws, size_t ws_size,
                              hipStream_t stream)
{
    const float* x = (const float*)d_in[0];
    const float* y = (const float*)d_in[1];
    float* out  = (float*)d_out;
    float* part = (float*)d_ws;   // 4096 floats = 16 KB << ws_size

    const long long total = (long long)in_sizes[0];       // 32*1024*1024
    const int N = (int)(total / ((long long)IMG_H * IMG_W));
    const int nparts = (IMG_H / RPB) * N;

    dim3 grid(IMG_H / RPB, N);
    ssim_map_sum_kernel<<<grid, TPB, 0, stream>>>(x, y, part);

    ssim_finalize_kernel<<<1, 256, 0, stream>>>(part, nparts, out, 1.0f / (float)total);
}